// Round 1
// baseline (902.637 us; speedup 1.0000x reference)
//
#include <hip/hip_runtime.h>
#include <math.h>

#define NROWS 524288
#define DIN 64
#define HD 128
#define DZ 16
#define KC 256
#define BETA 0.25f

#define TILE_R 64
#define NTHR 256

// LDS layout (floats). Two 8192-float regions, 64KB total static LDS -> 2 blocks/CU.
// region0: sF (feats tile, 64x64 pitch 65) then sH2 (64x128 XOR-swizzled)
// region1: sH1 (64x128 XOR-swizzled) then phase-C scratch (cnorm/Lvs/Zs/best)
#define REG0 0
#define REG1 8192
#define SMEM_FLOATS 16384

// XOR swizzle keeps pitch 128 (so region fits 8192 floats) while making both
// row-broadcast reads (fixed k, lanes vary r) and column writes conflict-free:
// bank = (k ^ r) % 32 -> 2 lanes/bank for wave64 = free (m136).
__device__ __forceinline__ int swz(int rr, int kk) {
  return rr * 128 + ((kk ^ rr) & 127);
}

__global__ __launch_bounds__(NTHR, 2)
void encoder_main(const float* __restrict__ feats,
                  const float* __restrict__ W1, const float* __restrict__ b1,
                  const float* __restrict__ W2, const float* __restrict__ b2,
                  const float* __restrict__ Wmu, const float* __restrict__ bmu,
                  const float* __restrict__ Wlv, const float* __restrict__ blv,
                  const float* __restrict__ codebook,
                  const float* __restrict__ eps,
                  float* __restrict__ out, float* __restrict__ loss_ws)
{
  __shared__ float smem[SMEM_FLOATS];
  float* sF  = smem + REG0;                   // 64 x 64, pitch 65 (4160 floats)
  float* sH2 = smem + REG0;                   // 64 x 128 swizzled (overlays sF, live after phase B)
  float* sH1 = smem + REG1;                   // 64 x 128 swizzled
  float* cnormS = smem + REG1;                // 256 (overlays dead sH1 in phase C)
  float* Lvs    = smem + REG1 + 256;          // 64 x 17
  float* Zs     = smem + REG1 + 1344;         // 64 x 17
  float* bestdS = smem + REG1 + 2432;         // 256
  int*   bestiS = (int*)(smem + REG1 + 2688); // 256

  const int t = threadIdx.x;
  const int r = t & 63;                       // row within tile; lane id within wave
  // wave id, provably uniform -> weight addresses become SGPR -> s_load path
  const int wv = __builtin_amdgcn_readfirstlane(t >> 6);
  const int row0 = blockIdx.x * TILE_R;

  // ---- stage feats tile (coalesced float4) ----
  {
    const float4* src = (const float4*)(feats + (size_t)row0 * DIN);
    #pragma unroll
    for (int i = 0; i < 4; ++i) {
      int v = t + i * NTHR;                   // float4 index 0..1023
      float4 f4 = src[v];
      int rr = v >> 4;                        // 16 float4 per row
      int cc = (v & 15) * 4;
      float* dst = sF + rr * 65 + cc;         // pitch 65: (r+k)%32 banks, conflict-free
      dst[0] = f4.x; dst[1] = f4.y; dst[2] = f4.z; dst[3] = f4.w;
    }
  }
  __syncthreads();

  // ---- phase A: h1 = relu(feats @ W1 + b1); thread = (row r, 32 cols at wv*32) ----
  {
    const int j0 = wv * 32;
    float acc[32];
    const float* __restrict__ bb = b1 + j0;   // uniform -> scalar loads
    #pragma unroll
    for (int i = 0; i < 32; ++i) acc[i] = bb[i];
    for (int k = 0; k < DIN; ++k) {
      float f = sF[r * 65 + k];
      const float* __restrict__ wrow = W1 + k * HD + j0;  // uniform -> s_load
      #pragma unroll
      for (int i = 0; i < 32; ++i) acc[i] = fmaf(f, wrow[i], acc[i]);
    }
    #pragma unroll
    for (int i = 0; i < 32; ++i) sH1[swz(r, j0 + i)] = fmaxf(acc[i], 0.0f);
  }
  __syncthreads();

  // ---- phase B: h2 = relu(h1 @ W2 + b2) ----
  {
    const int j0 = wv * 32;
    float acc[32];
    const float* __restrict__ bb = b2 + j0;
    #pragma unroll
    for (int i = 0; i < 32; ++i) acc[i] = bb[i];
    for (int k = 0; k < HD; ++k) {
      float f = sH1[swz(r, k)];
      const float* __restrict__ wrow = W2 + k * HD + j0;  // uniform -> s_load
      #pragma unroll
      for (int i = 0; i < 32; ++i) acc[i] = fmaf(f, wrow[i], acc[i]);
    }
    #pragma unroll
    for (int i = 0; i < 32; ++i) sH2[swz(r, j0 + i)] = fmaxf(acc[i], 0.0f);
  }
  __syncthreads();

  // ---- codebook squared norms (one code per thread; sH1 region now dead) ----
  {
    const float4* crow = (const float4*)(codebook + t * DZ);
    float4 a = crow[0], b = crow[1], c = crow[2], d = crow[3];
    cnormS[t] = a.x*a.x + a.y*a.y + a.z*a.z + a.w*a.w
              + b.x*b.x + b.y*b.y + b.z*b.z + b.w*b.w
              + c.x*c.x + c.y*c.y + c.z*c.z + c.w*c.w
              + d.x*d.x + d.y*d.y + d.z*d.z + d.w*d.w;
  }

  // ---- phase C: heads. wv0/1 -> mu cols 0..7 / 8..15 ; wv2/3 -> lv ----
  {
    const int c0 = (wv & 1) * 8;
    const int is_mu = (wv < 2);
    const float* __restrict__ Wh = is_mu ? Wmu : Wlv;
    const float* __restrict__ bh = is_mu ? bmu : blv;
    float acc[8];
    #pragma unroll
    for (int i = 0; i < 8; ++i) acc[i] = bh[c0 + i];
    for (int k = 0; k < HD; ++k) {
      float h = sH2[swz(r, k)];
      const float* __restrict__ wrow = Wh + k * DZ + c0;  // uniform -> s_load
      #pragma unroll
      for (int i = 0; i < 8; ++i) acc[i] = fmaf(h, wrow[i], acc[i]);
    }
    const size_t base = (size_t)(row0 + r) * DZ + c0;
    if (!is_mu) {
      #pragma unroll
      for (int i = 0; i < 8; ++i) Lvs[r * 17 + c0 + i] = acc[i];
      float4* g = (float4*)(out + (size_t)2 * NROWS * DZ + base);
      g[0] = make_float4(acc[0], acc[1], acc[2], acc[3]);
      g[1] = make_float4(acc[4], acc[5], acc[6], acc[7]);
    }
    __syncthreads();   // Lvs + cnormS visible
    if (is_mu) {
      float4* gmu = (float4*)(out + (size_t)NROWS * DZ + base);
      gmu[0] = make_float4(acc[0], acc[1], acc[2], acc[3]);
      gmu[1] = make_float4(acc[4], acc[5], acc[6], acc[7]);
      const float4* ge = (const float4*)(eps + base);
      float4 e0 = ge[0], e1 = ge[1];
      float ev[8] = {e0.x, e0.y, e0.z, e0.w, e1.x, e1.y, e1.z, e1.w};
      float zv[8];
      #pragma unroll
      for (int i = 0; i < 8; ++i) {
        float lvv = Lvs[r * 17 + c0 + i];
        zv[i] = fmaf(ev[i], expf(0.5f * lvv), acc[i]);   // precise expf: keep z close to ref
        Zs[r * 17 + c0 + i] = zv[i];
      }
      float4* gz = (float4*)(out + base);
      gz[0] = make_float4(zv[0], zv[1], zv[2], zv[3]);
      gz[1] = make_float4(zv[4], zv[5], zv[6], zv[7]);
    }
    __syncthreads();   // Zs visible
  }

  // ---- VQ: 4 threads/row, each scans 64 codes; argmin == first-min (ascending) ----
  {
    float zreg[16];
    #pragma unroll
    for (int i = 0; i < 16; ++i) zreg[i] = Zs[r * 17 + i];  // pitch 17: conflict-free
    const int kk0 = wv * 64;
    float bd = 3.0e38f;
    int bi = kk0;
    for (int c = 0; c < 64; ++c) {
      int kk = kk0 + c;
      const float* __restrict__ crow = codebook + kk * DZ;  // uniform -> s_load_dwordx16
      float dot = 0.0f;
      #pragma unroll
      for (int i = 0; i < 16; ++i) dot = fmaf(zreg[i], crow[i], dot);
      float s = fmaf(-2.0f, dot, cnormS[kk]);  // argmin of (cnorm - 2 z.c) == argmin dist
      if (s < bd) { bd = s; bi = kk; }          // strict <: keeps lowest index
    }
    bestdS[wv * 64 + r] = bd;
    bestiS[wv * 64 + r] = bi;
  }
  __syncthreads();

  // ---- merge, gather z_q, loss ----
  if (t < 64) {   // exactly wave 0
    float bd = bestdS[r];
    int   bi = bestiS[r];
    #pragma unroll
    for (int g = 1; g < 4; ++g) {   // ascending groups: strict < preserves lowest index on ties
      float d2 = bestdS[g * 64 + r];
      int   i2 = bestiS[g * 64 + r];
      if (d2 < bd) { bd = d2; bi = i2; }
    }
    const float4* cq = (const float4*)(codebook + bi * DZ);  // lane-varying, L1-hot
    float4 q0 = cq[0], q1 = cq[1], q2 = cq[2], q3 = cq[3];
    const size_t base = (size_t)(row0 + r) * DZ;
    float4* gq = (float4*)(out + (size_t)3 * NROWS * DZ + base);
    gq[0] = q0; gq[1] = q1; gq[2] = q2; gq[3] = q3;

    float qq[16] = {q0.x,q0.y,q0.z,q0.w, q1.x,q1.y,q1.z,q1.w,
                    q2.x,q2.y,q2.z,q2.w, q3.x,q3.y,q3.z,q3.w};
    float lsum = 0.0f;
    #pragma unroll
    for (int i = 0; i < 16; ++i) {
      float d = qq[i] - Zs[r * 17 + i];
      lsum = fmaf(d, d, lsum);
    }
    // wave64 shuffle reduction -> one atomic per block
    #pragma unroll
    for (int off = 32; off > 0; off >>= 1) lsum += __shfl_down(lsum, off);
    if (t == 0) atomicAdd(loss_ws, lsum);
  }
}

__global__ void encoder_zero(float* ws) {
  if (threadIdx.x == 0 && blockIdx.x == 0) ws[0] = 0.0f;
}

__global__ void encoder_finalize(const float* __restrict__ ws, float* __restrict__ out) {
  if (threadIdx.x == 0 && blockIdx.x == 0) {
    // vq_loss = BETA * (commit + code) = 2*BETA*mean((zq-z)^2)
    out[(size_t)4 * NROWS * DZ] = ws[0] * (2.0f * BETA / (float)((size_t)NROWS * DZ));
  }
}

extern "C" void kernel_launch(void* const* d_in, const int* in_sizes, int n_in,
                              void* d_out, int out_size, void* d_ws, size_t ws_size,
                              hipStream_t stream) {
  (void)in_sizes; (void)n_in; (void)out_size; (void)ws_size;
  const float* feats    = (const float*)d_in[0];
  const float* W1       = (const float*)d_in[1];
  const float* b1       = (const float*)d_in[2];
  const float* W2       = (const float*)d_in[3];
  const float* b2       = (const float*)d_in[4];
  const float* Wmu      = (const float*)d_in[5];
  const float* bmu      = (const float*)d_in[6];
  const float* Wlv      = (const float*)d_in[7];
  const float* blv      = (const float*)d_in[8];
  const float* codebook = (const float*)d_in[9];
  const float* eps      = (const float*)d_in[10];
  float* out = (float*)d_out;
  float* ws  = (float*)d_ws;

  hipLaunchKernelGGL(encoder_zero, dim3(1), dim3(64), 0, stream, ws);
  hipLaunchKernelGGL(encoder_main, dim3(NROWS / TILE_R), dim3(NTHR), 0, stream,
                     feats, W1, b1, W2, b2, Wmu, bmu, Wlv, blv, codebook, eps, out, ws);
  hipLaunchKernelGGL(encoder_finalize, dim3(1), dim3(64), 0, stream, ws, out);
}

// Round 2
// 620.413 us; speedup vs baseline: 1.4549x; 1.4549x over previous
//
#include <hip/hip_runtime.h>
#include <math.h>

#define NROWS 524288
#define DIN 64
#define HD 128
#define DZ 16
#define KC 256
#define BETA 0.25f

#define TILE_R 64
#define NTHR 512
#define NWAVE 8

// ---- LDS layout (floats) ----
// region1: sH 64x129 (h1, then h2 in-place after a read-drain barrier)
// region0: sF 64x65 (feats tile) -> dead after phase A -> phase-C scratch overlays
#define SH_PITCH 129
#define SF_PITCH 65
#define REG1_SZ (TILE_R * SH_PITCH)          // 8256
#define REG0_SZ (TILE_R * SF_PITCH)          // 4160
#define SMEM_FLOATS (REG1_SZ + REG0_SZ)      // 12416 floats = 49664 B -> 3 blocks/CU

// scratch offsets inside region0 (after sF is dead)
#define OFF_CNORM 0                          // 256
#define OFF_LVS   256                        // 64x17 = 1088
#define OFF_ZS    (OFF_LVS + TILE_R * 17)    // 1344, 64x17 = 1088
#define OFF_BESTD (OFF_ZS + TILE_R * 17)     // 2432, 512
#define OFF_BESTI (OFF_BESTD + NWAVE * 64)   // 2944, 512  (end 3456 <= 4160)

__global__ __launch_bounds__(NTHR, 4)
void encoder_main(const float* __restrict__ feats,
                  const float* __restrict__ W1, const float* __restrict__ b1,
                  const float* __restrict__ W2, const float* __restrict__ b2,
                  const float* __restrict__ Wmu, const float* __restrict__ bmu,
                  const float* __restrict__ Wlv, const float* __restrict__ blv,
                  const float* __restrict__ codebook,
                  const float* __restrict__ eps,
                  float* __restrict__ out, float* __restrict__ loss_ws)
{
  __shared__ float smem[SMEM_FLOATS];
  float* sH = smem;                    // region1: h1 then h2 (in-place)
  float* sF = smem + REG1_SZ;          // region0: feats tile
  float* cnormS = sF + OFF_CNORM;
  float* Lvs    = sF + OFF_LVS;
  float* Zs     = sF + OFF_ZS;
  float* bestdS = sF + OFF_BESTD;
  int*   bestiS = (int*)(sF + OFF_BESTI);

  const int t = threadIdx.x;
  const int r = t & 63;                                   // row in tile == lane id
  const int wv = __builtin_amdgcn_readfirstlane(t >> 6);  // wave id 0..7, uniform
  const int row0 = blockIdx.x * TILE_R;

  // ---- stage feats tile (coalesced float4; 1024 float4 / 512 thr = 2 each) ----
  {
    const float4* src = (const float4*)(feats + (size_t)row0 * DIN);
    #pragma unroll
    for (int i = 0; i < 2; ++i) {
      int v = t + i * NTHR;             // float4 index 0..1023
      float4 f4 = src[v];
      int rr = v >> 4;                  // 16 float4 per row
      int cc = (v & 15) * 4;
      float* dst = sF + rr * SF_PITCH + cc;
      dst[0] = f4.x; dst[1] = f4.y; dst[2] = f4.z; dst[3] = f4.w;
    }
  }
  __syncthreads();

  // ---- phase A: h1 = relu(feats @ W1 + b1); thread = (row r, 16 cols @ wv*16) ----
  {
    const int j0 = wv * 16;
    float acc[16];
    const float* __restrict__ bb = b1 + j0;               // uniform -> scalar
    #pragma unroll
    for (int i = 0; i < 16; ++i) acc[i] = bb[i];
    for (int k = 0; k < DIN; ++k) {
      float f = sF[r * SF_PITCH + k];                     // (r+k)%32 banks: free
      const float* __restrict__ wrow = W1 + k * HD + j0;  // uniform -> s_load
      #pragma unroll
      for (int i = 0; i < 16; ++i) acc[i] = fmaf(f, wrow[i], acc[i]);
    }
    #pragma unroll
    for (int i = 0; i < 16; ++i) sH[r * SH_PITCH + j0 + i] = fmaxf(acc[i], 0.0f);
  }
  __syncthreads();   // barrier1: A done; sF dead -> scratch writable; h1 readable

  // ---- codebook norms (one code per thread, t<256; writes scratch region0) ----
  if (t < KC) {
    const float4* crow = (const float4*)(codebook + t * DZ);
    float4 a = crow[0], b = crow[1], c = crow[2], d = crow[3];
    cnormS[t] = a.x*a.x + a.y*a.y + a.z*a.z + a.w*a.w
              + b.x*b.x + b.y*b.y + b.z*b.z + b.w*b.w
              + c.x*c.x + c.y*c.y + c.z*c.z + c.w*c.w
              + d.x*d.x + d.y*d.y + d.z*d.z + d.w*d.w;
  }

  // ---- phase B: h2 = relu(h1 @ W2 + b2), in-place over sH ----
  {
    const int j0 = wv * 16;
    float acc[16];
    const float* __restrict__ bb = b2 + j0;
    #pragma unroll
    for (int i = 0; i < 16; ++i) acc[i] = bb[i];
    for (int k = 0; k < HD; ++k) {
      float f = sH[r * SH_PITCH + k];                     // (r+k)%32: free
      const float* __restrict__ wrow = W2 + k * HD + j0;  // uniform -> s_load
      #pragma unroll
      for (int i = 0; i < 16; ++i) acc[i] = fmaf(f, wrow[i], acc[i]);
    }
    __syncthreads();  // barrier2: ALL h1 reads complete before overwrite
    #pragma unroll
    for (int i = 0; i < 16; ++i) sH[r * SH_PITCH + j0 + i] = fmaxf(acc[i], 0.0f);
  }
  __syncthreads();   // barrier3: h2 visible

  // ---- phase C: heads. wv0-3 -> mu (4 cols each), wv4-7 -> lv ----
  {
    const int c0 = (wv & 3) * 4;
    const int is_mu = (wv < 4);
    const float* __restrict__ Wh = is_mu ? Wmu : Wlv;
    const float* __restrict__ bh = is_mu ? bmu : blv;
    float acc[4];
    #pragma unroll
    for (int i = 0; i < 4; ++i) acc[i] = bh[c0 + i];
    for (int k = 0; k < HD; ++k) {
      float h = sH[r * SH_PITCH + k];
      const float* __restrict__ wrow = Wh + k * DZ + c0;  // uniform -> s_load
      #pragma unroll
      for (int i = 0; i < 4; ++i) acc[i] = fmaf(h, wrow[i], acc[i]);
    }
    const size_t base = (size_t)(row0 + r) * DZ + c0;
    if (!is_mu) {
      #pragma unroll
      for (int i = 0; i < 4; ++i) Lvs[r * 17 + c0 + i] = acc[i];
      float4* g = (float4*)(out + (size_t)2 * NROWS * DZ + base);
      g[0] = make_float4(acc[0], acc[1], acc[2], acc[3]);
    } else {
      float4* gmu = (float4*)(out + (size_t)NROWS * DZ + base);
      gmu[0] = make_float4(acc[0], acc[1], acc[2], acc[3]);
    }
    __syncthreads();   // barrier4: Lvs visible
    if (is_mu) {
      const float4* ge = (const float4*)(eps + base);
      float4 e0 = ge[0];
      float ev[4] = {e0.x, e0.y, e0.z, e0.w};
      float zv[4];
      #pragma unroll
      for (int i = 0; i < 4; ++i) {
        float lvv = Lvs[r * 17 + c0 + i];
        zv[i] = fmaf(ev[i], expf(0.5f * lvv), acc[i]);
        Zs[r * 17 + c0 + i] = zv[i];
      }
      float4* gz = (float4*)(out + base);
      gz[0] = make_float4(zv[0], zv[1], zv[2], zv[3]);
    }
    __syncthreads();   // barrier5: Zs visible
  }

  // ---- VQ: 8 threads/row, each scans 32 codes (ascending; strict < = argmin) ----
  {
    float zreg[16];
    #pragma unroll
    for (int i = 0; i < 16; ++i) zreg[i] = Zs[r * 17 + i];
    const int kk0 = wv * 32;
    float bd = 3.0e38f;
    int bi = kk0;
    for (int c = 0; c < 32; ++c) {
      int kk = kk0 + c;
      const float* __restrict__ crow = codebook + kk * DZ;  // uniform -> s_load
      float dot = 0.0f;
      #pragma unroll
      for (int i = 0; i < 16; ++i) dot = fmaf(zreg[i], crow[i], dot);
      float s = fmaf(-2.0f, dot, cnormS[kk]);
      if (s < bd) { bd = s; bi = kk; }
    }
    bestdS[wv * 64 + r] = bd;
    bestiS[wv * 64 + r] = bi;
  }
  __syncthreads();   // barrier6

  // ---- merge (wave 0), gather z_q, loss ----
  if (t < 64) {
    float bd = bestdS[r];
    int   bi = bestiS[r];
    #pragma unroll
    for (int g = 1; g < NWAVE; ++g) {   // ascending groups, strict <: lowest idx wins ties
      float d2 = bestdS[g * 64 + r];
      int   i2 = bestiS[g * 64 + r];
      if (d2 < bd) { bd = d2; bi = i2; }
    }
    const float4* cq = (const float4*)(codebook + bi * DZ);
    float4 q0 = cq[0], q1 = cq[1], q2 = cq[2], q3 = cq[3];
    const size_t base = (size_t)(row0 + r) * DZ;
    float4* gq = (float4*)(out + (size_t)3 * NROWS * DZ + base);
    gq[0] = q0; gq[1] = q1; gq[2] = q2; gq[3] = q3;

    float qq[16] = {q0.x,q0.y,q0.z,q0.w, q1.x,q1.y,q1.z,q1.w,
                    q2.x,q2.y,q2.z,q2.w, q3.x,q3.y,q3.z,q3.w};
    float lsum = 0.0f;
    #pragma unroll
    for (int i = 0; i < 16; ++i) {
      float d = qq[i] - Zs[r * 17 + i];
      lsum = fmaf(d, d, lsum);
    }
    #pragma unroll
    for (int off = 32; off > 0; off >>= 1) lsum += __shfl_down(lsum, off);
    if (t == 0) atomicAdd(loss_ws, lsum);
  }
}

__global__ void encoder_zero(float* ws) {
  if (threadIdx.x == 0 && blockIdx.x == 0) ws[0] = 0.0f;
}

__global__ void encoder_finalize(const float* __restrict__ ws, float* __restrict__ out) {
  if (threadIdx.x == 0 && blockIdx.x == 0) {
    // vq_loss = BETA * (commit + code) = 2*BETA*mean((zq-z)^2)
    out[(size_t)4 * NROWS * DZ] = ws[0] * (2.0f * BETA / (float)((size_t)NROWS * DZ));
  }
}

extern "C" void kernel_launch(void* const* d_in, const int* in_sizes, int n_in,
                              void* d_out, int out_size, void* d_ws, size_t ws_size,
                              hipStream_t stream) {
  (void)in_sizes; (void)n_in; (void)out_size; (void)ws_size;
  const float* feats    = (const float*)d_in[0];
  const float* W1       = (const float*)d_in[1];
  const float* b1       = (const float*)d_in[2];
  const float* W2       = (const float*)d_in[3];
  const float* b2       = (const float*)d_in[4];
  const float* Wmu      = (const float*)d_in[5];
  const float* bmu      = (const float*)d_in[6];
  const float* Wlv      = (const float*)d_in[7];
  const float* blv      = (const float*)d_in[8];
  const float* codebook = (const float*)d_in[9];
  const float* eps      = (const float*)d_in[10];
  float* out = (float*)d_out;
  float* ws  = (float*)d_ws;

  hipLaunchKernelGGL(encoder_zero, dim3(1), dim3(64), 0, stream, ws);
  hipLaunchKernelGGL(encoder_main, dim3(NROWS / TILE_R), dim3(NTHR), 0, stream,
                     feats, W1, b1, W2, b2, Wmu, bmu, Wlv, blv, codebook, eps, out, ws);
  hipLaunchKernelGGL(encoder_finalize, dim3(1), dim3(64), 0, stream, ws, out);
}